// Round 8
// baseline (351.086 us; speedup 1.0000x reference)
//
#include <hip/hip_runtime.h>
#include <stdint.h>

#define N_NODES 100000
#define N_EDGES 320000
#define DIM 256
#define BN_EPS 1e-5f

typedef __attribute__((ext_vector_type(8))) short short8;
typedef __attribute__((ext_vector_type(4))) float f32x4;

__device__ __forceinline__ float bf2f(unsigned short u) {
    union { unsigned int i; float f; } v; v.i = ((unsigned int)u) << 16; return v.f;
}
__device__ __forceinline__ unsigned short f2bf(float f) {
    union { float f; unsigned int i; } v; v.f = f;
    unsigned int x = v.i;
    return (unsigned short)((x + 0x7fffu + ((x >> 16) & 1u)) >> 16);  // RNE
}
__device__ __forceinline__ int eidx(const int* ei, int i64, int which, int e) {
    int idx = which * N_EDGES + e;
    return i64 ? ei[idx * 2] : ei[idx];
}
__device__ __forceinline__ f32x4 ldx4(const void* xv, int xf32, size_t off) {
    if (xf32) return *(const f32x4*)((const float*)xv + off);
    uint2 u = *(const uint2*)((const unsigned short*)xv + off);
    f32x4 o;
    o[0] = bf2f((unsigned short)(u.x & 0xffffu));
    o[1] = bf2f((unsigned short)(u.x >> 16));
    o[2] = bf2f((unsigned short)(u.y & 0xffffu));
    o[3] = bf2f((unsigned short)(u.y >> 16));
    return o;
}

// ---- init: zero cnt/stats; block 0 also runs dtype detection ----
__global__ void k_init(const unsigned short* __restrict__ xs,
                       const unsigned short* __restrict__ wsw,
                       const int* __restrict__ ei, int* __restrict__ flags,
                       int* __restrict__ cnt, float* __restrict__ stats) {
    __shared__ int red[3];
    int t = threadIdx.x;
    int i = blockIdx.x * 256 + t;
    if (i < N_NODES) cnt[i] = 0;
    if (i < 512) stats[i] = 0.0f;
    if (blockIdx.x == 0) {
        if (t < 3) red[t] = 0;
        __syncthreads();
        int badx = 0, badw = 0, nz = 0;
        for (int j = 0; j < 8; ++j) {
            if (!(fabsf(bf2f(xs[t * 8 + j])) <= 1000.0f)) badx = 1;
            if (!(fabsf(bf2f(wsw[t * 8 + j])) <= 1000.0f)) badw = 1;
            if (ei[(t * 8 + j) * 2 + 1] != 0) nz = 1;
        }
        if (badx) atomicOr(&red[0], 1);
        if (badw) atomicOr(&red[1], 1);
        if (nz)   atomicOr(&red[2], 1);
        __syncthreads();
        if (t == 0) { flags[0] = red[0]; flags[1] = red[1]; flags[2] = red[2] ? 0 : 1; }
    }
}

// ---- fused: degree count (blocks 0..1249) + W transpose/split (1250..1505) ----
__global__ void k_cntwt(const int* __restrict__ ei, int* __restrict__ cnt,
                        const void* __restrict__ wv, unsigned short* __restrict__ Wth,
                        unsigned short* __restrict__ Wtl, const int* __restrict__ flags) {
    int b = blockIdx.x, t = threadIdx.x;
    if (b < 1250) {
        int i64 = flags[2];
        int e = b * 256 + t;
        if (e < N_EDGES) atomicAdd(&cnt[eidx(ei, i64, 1, e)], 1);
    } else {
        int wf32 = flags[1];
        int k = b - 1250, n = t;
        float v = wf32 ? ((const float*)wv)[k * DIM + n]
                       : bf2f(((const unsigned short*)wv)[k * DIM + n]);
        unsigned short h = f2bf(v);
        Wth[(size_t)n * DIM + k] = h;
        Wtl[(size_t)n * DIM + k] = f2bf(v - bf2f(h));
    }
}

// ---- fused: dinv (all 391 blocks) + per-chunk partial sums (blocks < 200) ----
__global__ void k_dscan(const int* __restrict__ cnt, float* __restrict__ dinv,
                        int* __restrict__ partial) {
    __shared__ int red[256];
    int t = threadIdx.x, b = blockIdx.x;
    int i = b * 256 + t;
    if (i < N_NODES) dinv[i] = rsqrtf((float)cnt[i] + 1.0f);   // +1 self-loop
    if (b < 200) {
        int i0 = b * 512 + t * 2;
        int s = 0;
        if (i0 < N_NODES) s += cnt[i0];
        if (i0 + 1 < N_NODES) s += cnt[i0 + 1];
        red[t] = s;
        __syncthreads();
        for (int off = 128; off > 0; off >>= 1) {
            if (t < off) red[t] += red[t + off];
            __syncthreads();
        }
        if (t == 0) partial[b] = red[0];
    }
}

// ---- merged scan: each block redundantly scans the 200 partials in LDS
// (replaces the separate k_scan2 launch), then scans its own 512-chunk ----
__global__ void k_scan23(const int* __restrict__ cnt, const int* __restrict__ partial,
                         int* __restrict__ row_start, int* __restrict__ cursor) {
    __shared__ int sp[256];
    __shared__ int s[512];
    __shared__ int base;
    int t = threadIdx.x, b = blockIdx.x;
    if (t < 256) sp[t] = (t < 200) ? partial[t] : 0;
    __syncthreads();
    for (int off = 1; off < 256; off <<= 1) {
        int u = 0;
        if (t < 256 && t >= off) u = sp[t - off];
        __syncthreads();
        if (t < 256) sp[t] += u;
        __syncthreads();
    }
    if (t == 0) base = (b == 0) ? 0 : sp[b - 1];   // exclusive chunk base
    // per-chunk exclusive scan over 512 nodes
    int i = b * 512 + t;
    int v = (i < N_NODES) ? cnt[i] : 0;
    s[t] = v;
    __syncthreads();
    for (int off = 1; off < 512; off <<= 1) {
        int u = (t >= off) ? s[t - off] : 0;
        __syncthreads();
        s[t] += u;
        __syncthreads();
    }
    if (i < N_NODES) {
        int excl = base + s[t] - v;
        row_start[i] = excl;
        cursor[i] = excl;
    }
}

// ---- CSR fill: slot per edge; packed (src, norm) ----
__global__ void k_fill(const int* __restrict__ ei, const float* __restrict__ dinv,
                       int* __restrict__ cursor, int2* __restrict__ csr_pk,
                       const int* __restrict__ flags) {
    int i64 = flags[2];
    int e = blockIdx.x * 256 + threadIdx.x;
    if (e >= N_EDGES) return;
    int c = eidx(ei, i64, 1, e);
    int r = eidx(ei, i64, 0, e);
    int slot = atomicAdd(&cursor[c], 1);
    union { float f; int i; } u; u.f = dinv[r] * dinv[c];
    int2 pk; pk.x = r; pk.y = u.i;
    csr_pk[slot] = pk;
}

// =====================================================================
// FUSED aggregate + GEMM. 2084 blocks x 512 threads; block owns 48 rows
// (wave: 6 nodes gather, 32 output cols GEMM). LDS 48KB -> 3 blocks/CU
// = 24 waves/CU (launch_bounds 512,6 caps VGPR at 85).
// Gather is 2-deep pipelined: while node n accumulates, node n+1's x
// gathers are already in flight (its csr_pk arrived one iter earlier)
// and node n+2's csr_pk is being fetched. fp32 path only (bf16 input
// falls back to the 1-deep loop).
// =====================================================================
__launch_bounds__(512, 6)
__global__ void k_fused(const void* __restrict__ xv, const int* __restrict__ row_start,
                        const int* __restrict__ cnt, const int2* __restrict__ csr_pk,
                        const float* __restrict__ dinv,
                        const unsigned short* __restrict__ Wth,
                        const unsigned short* __restrict__ Wtl,
                        float* __restrict__ out, float* __restrict__ stats,
                        const int* __restrict__ flags) {
    __shared__ unsigned short zsh[48 * 256];   // 24576 B, hi
    __shared__ unsigned short zsl[48 * 256];   // 24576 B, lo
    int tid = threadIdx.x;
    int m0l = blockIdx.x * 48;
    int w = tid >> 6, lane = tid & 63, quad = lane >> 4, rl = lane & 15;
    int xf32 = flags[0];
    size_t lo4 = (size_t)(lane * 4);

    const int NPW = 6;
    int nb0 = m0l + w * NPW;
    // lanes 0..5 hold the wave's 6 nodes' meta
    int mstart = 0, mlen = 0; float mdv = 0.f;
    if (lane < NPW && nb0 + lane < N_NODES) {
        mstart = row_start[nb0 + lane];
        mlen   = cnt[nb0 + lane];
        mdv    = dinv[nb0 + lane];
    }

    if (xf32) {
        const float* xp = (const float*)xv;
        // pipeline state: A = accumulating now (x loads in flight),
        //                 B = next (pk arrived -> derive+issue inside loop)
        int myiA = 0, myiB = 0; float mynA = 0.f, mynB = 0.f;
        int lnA = 0, lnB = 0, stA = 0, stB = 0; float sA = 0.f, sB = 0.f;
        float nwA[4], nwB[4];
        f32x4 xA[4], xB[4];
        int2 pkB, pkN;

        {   // prologue: node 0 derive+issue; node 1 pk issue
            int st = __shfl(mstart, 0), ln = __shfl(mlen, 0);
            float dv = __shfl(mdv, 0);
            int2 pk; pk.x = 0; pk.y = 0;
            if (lane < ln) pk = csr_pk[st + lane];
            myiA = (nb0 < N_NODES) ? nb0 : 0;
            mynA = 0.f; sA = dv * dv; lnA = ln; stA = st;
            if (lane < ln) { myiA = pk.x; union { int i; float f; } u; u.i = pk.y; mynA = u.f; }
            if (ln <= 63 && lane == ln) mynA = sA;
            #pragma unroll
            for (int j = 0; j < 4; ++j) {
                int ii = __shfl(myiA, j); nwA[j] = __shfl(mynA, j);
                xA[j] = *(const f32x4*)(xp + (size_t)ii * DIM + lo4);
            }
            int st1 = __shfl(mstart, 1), ln1 = __shfl(mlen, 1);
            pkB.x = 0; pkB.y = 0;
            if (lane < ln1) pkB = csr_pk[st1 + lane];
        }

        #pragma unroll
        for (int nn = 0; nn < NPW; ++nn) {
            int row = w * NPW + nn;
            // ---- stage node nn+1: derive, issue x loads; start pk nn+2 ----
            if (nn + 1 < NPW) {
                int st = __shfl(mstart, nn + 1), ln = __shfl(mlen, nn + 1);
                float dv = __shfl(mdv, nn + 1);
                int noden = nb0 + nn + 1;
                myiB = (noden < N_NODES) ? noden : 0;
                mynB = 0.f; sB = dv * dv; lnB = ln; stB = st;
                if (lane < ln) { myiB = pkB.x; union { int i; float f; } u; u.i = pkB.y; mynB = u.f; }
                if (ln <= 63 && lane == ln) mynB = sB;
                #pragma unroll
                for (int j = 0; j < 4; ++j) {
                    int ii = __shfl(myiB, j); nwB[j] = __shfl(mynB, j);
                    xB[j] = *(const f32x4*)(xp + (size_t)ii * DIM + lo4);
                }
                if (nn + 2 < NPW) {
                    int st2 = __shfl(mstart, nn + 2), ln2 = __shfl(mlen, nn + 2);
                    pkN.x = 0; pkN.y = 0;
                    if (lane < ln2) pkN = csr_pk[st2 + lane];
                }
            }
            // ---- accumulate node nn (same 4-term association as before) ----
            f32x4 acc = (f32x4){0.f, 0.f, 0.f, 0.f};
            #pragma unroll
            for (int q = 0; q < 4; ++q)
                acc[q] += nwA[0] * xA[0][q] + nwA[1] * xA[1][q]
                        + nwA[2] * xA[2][q] + nwA[3] * xA[3][q];
            int n_eff = (lnA > 63) ? 64 : (lnA + 1);
            int npad = (n_eff + 3) & ~3;
            for (int j = 4; j < npad; j += 4) {
                int i0 = __shfl(myiA, j),     i1 = __shfl(myiA, j + 1);
                int i2 = __shfl(myiA, j + 2), i3 = __shfl(myiA, j + 3);
                float n0 = __shfl(mynA, j),     n1 = __shfl(mynA, j + 1);
                float n2 = __shfl(mynA, j + 2), n3 = __shfl(mynA, j + 3);
                f32x4 x0 = *(const f32x4*)(xp + (size_t)i0 * DIM + lo4);
                f32x4 x1 = *(const f32x4*)(xp + (size_t)i1 * DIM + lo4);
                f32x4 x2 = *(const f32x4*)(xp + (size_t)i2 * DIM + lo4);
                f32x4 x3 = *(const f32x4*)(xp + (size_t)i3 * DIM + lo4);
                #pragma unroll
                for (int q = 0; q < 4; ++q)
                    acc[q] += n0 * x0[q] + n1 * x1[q] + n2 * x2[q] + n3 * x3[q];
            }
            if (lnA > 63) {                       // cold: degree > 63
                int node = nb0 + nn;
                f32x4 xs = *(const f32x4*)(xp + (size_t)node * DIM + lo4);
                #pragma unroll
                for (int q = 0; q < 4; ++q) acc[q] += sA * xs[q];
                for (int t2 = 64; t2 < lnA; ++t2) {
                    int2 pk = csr_pk[stA + t2];
                    union { int i; float f; } u; u.i = pk.y;
                    f32x4 xr = *(const f32x4*)(xp + (size_t)pk.x * DIM + lo4);
                    #pragma unroll
                    for (int q = 0; q < 4; ++q) acc[q] += u.f * xr[q];
                }
            }
            // ---- emit split-bf16 to swizzled LDS ----
            unsigned short h0 = f2bf(acc[0]), h1 = f2bf(acc[1]);
            unsigned short h2 = f2bf(acc[2]), h3 = f2bf(acc[3]);
            uint2 vh, vl;
            vh.x = (unsigned int)h0 | ((unsigned int)h1 << 16);
            vh.y = (unsigned int)h2 | ((unsigned int)h3 << 16);
            vl.x = (unsigned int)f2bf(acc[0] - bf2f(h0))
                 | ((unsigned int)f2bf(acc[1] - bf2f(h1)) << 16);
            vl.y = (unsigned int)f2bf(acc[2] - bf2f(h2))
                 | ((unsigned int)f2bf(acc[3] - bf2f(h3)) << 16);
            int sl  = lane >> 1;
            int swz = (sl & 24) | ((sl & 7) ^ (row & 7));
            int offb = swz * 16 + (lane & 1) * 8;
            *(uint2*)((char*)zsh + (size_t)row * 512 + offb) = vh;
            *(uint2*)((char*)zsl + (size_t)row * 512 + offb) = vl;
            // ---- rotate B -> A ----
            if (nn + 1 < NPW) {
                myiA = myiB; mynA = mynB; lnA = lnB; sA = sB; stA = stB;
                #pragma unroll
                for (int j = 0; j < 4; ++j) { nwA[j] = nwB[j]; xA[j] = xB[j]; }
                pkB = pkN;
            }
        }
    } else {
        // bf16-x fallback: round-7 1-deep pipelined loop
        const unsigned short* xp = (const unsigned short*)xv;
        int start = __shfl(mstart, 0);
        int len   = __shfl(mlen, 0);
        float dv  = __shfl(mdv, 0);
        int2 pk_cur; pk_cur.x = 0; pk_cur.y = 0;
        if (lane < len) pk_cur = csr_pk[start + lane];
        for (int nn = 0; nn < NPW; ++nn) {
            int row = w * NPW + nn;
            int node = nb0 + nn;
            float s = dv * dv;
            int cstart = start, clen = len;
            int myi = (node < N_NODES) ? node : 0;
            float myn = 0.0f;
            if (lane < clen) {
                myi = pk_cur.x;
                union { int i; float f; } u; u.i = pk_cur.y;
                myn = u.f;
            }
            bool big = (clen > 63);
            int n_eff = big ? 64 : (clen + 1);
            if (!big && lane == clen) myn = s;
            int npad = (n_eff + 3) & ~3;
            if (nn + 1 < NPW) {
                start = __shfl(mstart, nn + 1);
                len   = __shfl(mlen, nn + 1);
                dv    = __shfl(mdv, nn + 1);
                int2 pk_n; pk_n.x = 0; pk_n.y = 0;
                if (lane < len) pk_n = csr_pk[start + lane];
                pk_cur = pk_n;
            }
            f32x4 acc = (f32x4){0.f, 0.f, 0.f, 0.f};
            for (int j = 0; j < npad; j += 4) {
                int i0 = __shfl(myi, j),     i1 = __shfl(myi, j + 1);
                int i2 = __shfl(myi, j + 2), i3 = __shfl(myi, j + 3);
                float n0 = __shfl(myn, j),     n1 = __shfl(myn, j + 1);
                float n2 = __shfl(myn, j + 2), n3 = __shfl(myn, j + 3);
                uint2 u0 = *(const uint2*)(xp + (size_t)i0 * DIM + lo4);
                uint2 u1 = *(const uint2*)(xp + (size_t)i1 * DIM + lo4);
                uint2 u2 = *(const uint2*)(xp + (size_t)i2 * DIM + lo4);
                uint2 u3 = *(const uint2*)(xp + (size_t)i3 * DIM + lo4);
                acc[0] += n0 * bf2f((unsigned short)(u0.x & 0xffffu))
                        + n1 * bf2f((unsigned short)(u1.x & 0xffffu))
                        + n2 * bf2f((unsigned short)(u2.x & 0xffffu))
                        + n3 * bf2f((unsigned short)(u3.x & 0xffffu));
                acc[1] += n0 * bf2f((unsigned short)(u0.x >> 16))
                        + n1 * bf2f((unsigned short)(u1.x >> 16))
                        + n2 * bf2f((unsigned short)(u2.x >> 16))
                        + n3 * bf2f((unsigned short)(u3.x >> 16));
                acc[2] += n0 * bf2f((unsigned short)(u0.y & 0xffffu))
                        + n1 * bf2f((unsigned short)(u1.y & 0xffffu))
                        + n2 * bf2f((unsigned short)(u2.y & 0xffffu))
                        + n3 * bf2f((unsigned short)(u3.y & 0xffffu));
                acc[3] += n0 * bf2f((unsigned short)(u0.y >> 16))
                        + n1 * bf2f((unsigned short)(u1.y >> 16))
                        + n2 * bf2f((unsigned short)(u2.y >> 16))
                        + n3 * bf2f((unsigned short)(u3.y >> 16));
            }
            if (big) {
                f32x4 xs = ldx4(xv, xf32, (size_t)node * DIM + lo4);
                #pragma unroll
                for (int q = 0; q < 4; ++q) acc[q] += s * xs[q];
                for (int t2 = 64; t2 < clen; ++t2) {
                    int2 pk = csr_pk[cstart + t2];
                    union { int i; float f; } u; u.i = pk.y;
                    f32x4 xr = ldx4(xv, xf32, (size_t)pk.x * DIM + lo4);
                    #pragma unroll
                    for (int q = 0; q < 4; ++q) acc[q] += u.f * xr[q];
                }
            }
            unsigned short h0 = f2bf(acc[0]), h1 = f2bf(acc[1]);
            unsigned short h2 = f2bf(acc[2]), h3 = f2bf(acc[3]);
            uint2 vh, vl;
            vh.x = (unsigned int)h0 | ((unsigned int)h1 << 16);
            vh.y = (unsigned int)h2 | ((unsigned int)h3 << 16);
            vl.x = (unsigned int)f2bf(acc[0] - bf2f(h0))
                 | ((unsigned int)f2bf(acc[1] - bf2f(h1)) << 16);
            vl.y = (unsigned int)f2bf(acc[2] - bf2f(h2))
                 | ((unsigned int)f2bf(acc[3] - bf2f(h3)) << 16);
            int sl  = lane >> 1;
            int swz = (sl & 24) | ((sl & 7) ^ (row & 7));
            int offb = swz * 16 + (lane & 1) * 8;
            *(uint2*)((char*)zsh + (size_t)row * 512 + offb) = vh;
            *(uint2*)((char*)zsl + (size_t)row * 512 + offb) = vl;
        }
    }
    __syncthreads();

    // ---- phase 2: GEMM from LDS (split-bf16, 3 MFMAs), K=256 ----
    f32x4 cacc[3][2];
    #pragma unroll
    for (int ms = 0; ms < 3; ++ms)
        #pragma unroll
        for (int nt = 0; nt < 2; ++nt)
            cacc[ms][nt] = (f32x4){0.f, 0.f, 0.f, 0.f};

    #pragma unroll
    for (int kk = 0; kk < 8; ++kk) {
        int k0g = kk * 32 + quad * 8;
        short8 bh[2], bl[2];
        #pragma unroll
        for (int nt = 0; nt < 2; ++nt) {
            int n = w * 32 + nt * 16 + rl;
            bh[nt] = *(const short8*)(Wth + (size_t)n * DIM + k0g);
            bl[nt] = *(const short8*)(Wtl + (size_t)n * DIM + k0g);
        }
        #pragma unroll
        for (int ms = 0; ms < 3; ++ms) {
            int row = ms * 16 + rl;
            int slot = kk * 4 + quad;
            int sl = (slot & 24) | ((slot & 7) ^ (row & 7));
            short8 ah = *(const short8*)((const char*)zsh + (size_t)row * 512 + sl * 16);
            short8 al = *(const short8*)((const char*)zsl + (size_t)row * 512 + sl * 16);
            #pragma unroll
            for (int nt = 0; nt < 2; ++nt) {
                cacc[ms][nt] = __builtin_amdgcn_mfma_f32_16x16x32_bf16(ah, bh[nt], cacc[ms][nt], 0, 0, 0);
                cacc[ms][nt] = __builtin_amdgcn_mfma_f32_16x16x32_bf16(al, bh[nt], cacc[ms][nt], 0, 0, 0);
                cacc[ms][nt] = __builtin_amdgcn_mfma_f32_16x16x32_bf16(ah, bl[nt], cacc[ms][nt], 0, 0, 0);
            }
        }
    }

    // C/D layout: col = lane&15 (n), row = quad*4 + reg (m)
    #pragma unroll
    for (int nt = 0; nt < 2; ++nt) {
        int col = w * 32 + nt * 16 + rl;
        float s1 = 0.f, s2 = 0.f;
        #pragma unroll
        for (int ms = 0; ms < 3; ++ms)
            #pragma unroll
            for (int i = 0; i < 4; ++i) {
                float v = cacc[ms][nt][i];
                s1 += v; s2 += v * v;
                int orow = m0l + ms * 16 + quad * 4 + i;
                if (orow < N_NODES)
                    out[(size_t)orow * DIM + col] = v;
            }
        s1 += __shfl_xor(s1, 16); s1 += __shfl_xor(s1, 32);
        s2 += __shfl_xor(s2, 16); s2 += __shfl_xor(s2, 32);
        if (lane < 16) {
            atomicAdd(&stats[col], s1);
            atomicAdd(&stats[256 + col], s2);
        }
    }
}

// ---- fused BN fold + normalize + tanh ----
__global__ void k_final(float* __restrict__ out, const float* __restrict__ stats,
                        const void* __restrict__ gv, const void* __restrict__ bv,
                        const int* __restrict__ flags) {
    __shared__ float ssc[256], ssh[256];
    int t = threadIdx.x;
    {
        int ff32 = flags[0];
        const float invN = 1.0f / (float)N_NODES;
        float mean = stats[t] * invN;
        float var = stats[256 + t] * invN - mean * mean;
        float g = ff32 ? ((const float*)gv)[t] : bf2f(((const unsigned short*)gv)[t]);
        float bb = ff32 ? ((const float*)bv)[t] : bf2f(((const unsigned short*)bv)[t]);
        float sc = g * rsqrtf(var + BN_EPS);
        ssc[t] = sc;
        ssh[t] = bb - mean * sc;
    }
    __syncthreads();
    int gt = blockIdx.x * 256 + t;
    int f0 = (gt & 63) * 4;
    size_t off = (size_t)gt * 4;
    f32x4 v = *(const f32x4*)(out + off);
    f32x4 o;
    #pragma unroll
    for (int j = 0; j < 4; ++j)
        o[j] = tanhf(v[j] * ssc[f0 + j] + ssh[f0 + j]);
    *(f32x4*)(out + off) = o;
}

extern "C" void kernel_launch(void* const* d_in, const int* in_sizes, int n_in,
                              void* d_out, int out_size, void* d_ws, size_t ws_size,
                              hipStream_t stream) {
    const void* x     = d_in[0];
    const void* W     = d_in[1];
    // d_in[2] = b: additive per-column constant, cancelled exactly by BatchNorm. Unused.
    const void* gamma = d_in[3];
    const void* beta  = d_in[4];
    const int* ei     = (const int*)d_in[5];
    float* out = (float*)d_out;   // fp32 output (validated round 3)

    char* ws = (char*)d_ws;
    int*   flags     = (int*)(ws);
    int*   cnt       = (int*)(ws + 4096);
    int*   row_start = (int*)(ws + 409600);
    int*   cursor    = (int*)(ws + 819200);
    float* dinv      = (float*)(ws + 1228800);
    int*   partial   = (int*)(ws + 1638400);
    float* stats     = (float*)(ws + 1654784);
    unsigned short* Wth = (unsigned short*)(ws + 1671168);
    unsigned short* Wtl = (unsigned short*)(ws + 1802240);
    int2*  csr_pk    = (int2*)(ws + 1933312);   // 320000*8B = 2.56MB

    const unsigned short* xs_us = (const unsigned short*)x;
    const unsigned short* W_us  = (const unsigned short*)W;

    k_init  <<<391,  256, 0, stream>>>(xs_us, W_us, ei, flags, cnt, stats);
    k_cntwt <<<1506, 256, 0, stream>>>(ei, cnt, W, Wth, Wtl, flags);
    k_dscan <<<391,  256, 0, stream>>>(cnt, dinv, partial);
    k_scan23<<<200,  512, 0, stream>>>(cnt, partial, row_start, cursor);
    k_fill  <<<1250, 256, 0, stream>>>(ei, dinv, cursor, csr_pk, flags);

    k_fused <<<2084, 512, 0, stream>>>(x, row_start, cnt, csr_pk, dinv,
                                       Wth, Wtl, out, stats, flags);

    k_final <<<25000, 256, 0, stream>>>(out, stats, gamma, beta, flags);
}